// Round 12
// baseline (481.289 us; speedup 1.0000x reference)
//
#include <hip/hip_runtime.h>

typedef __attribute__((ext_vector_type(8))) __bf16  bf16x8;
typedef __attribute__((ext_vector_type(8))) short   short8;
typedef __attribute__((ext_vector_type(4))) float   f32x4;

#define DM   512
#define BN   64                 // e-cols per block
#define NNT  8                  // 512/64 col strips
#define NKT2 8                  // [64 rows][64 k] double-tiles per strip
#define TILEB (64*64*2)         // 8 KiB per tile

__device__ __forceinline__ short f2bf(float f) {
  union { float f; unsigned u; } v; v.f = f;
  unsigned r = v.u + 0x7fffu + ((v.u >> 16) & 1u);   // RNE
  return (short)(r >> 16);
}

// XOR swizzle within a [rows][64 bf16] tile (128B row stride): conflict-free.
__device__ __forceinline__ int swz(int r, int cbyte) {
  return (r * 128 + cbyte) ^ ((r & 7) << 4);
}

// Fold softmax(taps) + conv into per-head G[h][e][d], stored as pre-swizzled
// per-(h, nt64, kt2) 64x64 LDS tile images. 8 d's per thread.
__global__ void build_g_kernel(const float* __restrict__ w,
                               const float* __restrict__ fcw,
                               short* __restrict__ Gt) {
  int idx = blockIdx.x * 256 + threadIdx.x;   // 8*512*512/8 threads
  int h  = idx >> 15;
  int t  = idx & 32767;
  int e  = t >> 6;
  int d0 = (t & 63) << 3;
  float w0 = w[h*3+0], w1 = w[h*3+1], w2 = w[h*3+2];
  float mx = fmaxf(w0, fmaxf(w1, w2));
  float e0 = __expf(w0-mx), e1 = __expf(w1-mx), e2 = __expf(w2-mx);
  float inv = 1.0f / (e0 + e1 + e2);
  float w0n = e0*inv, w1n = e1*inv, w2n = e2*inv;
  const float* row = fcw + e * DM;
  float v[10];
  v[0] = (d0 > 0) ? row[d0-1] : 0.0f;
  float4 a = *(const float4*)(row + d0);
  float4 b = *(const float4*)(row + d0 + 4);
  v[1]=a.x; v[2]=a.y; v[3]=a.z; v[4]=a.w;
  v[5]=b.x; v[6]=b.y; v[7]=b.z; v[8]=b.w;
  v[9] = (d0 + 8 < DM) ? row[d0+8] : 0.0f;
  short8 sv;
  #pragma unroll
  for (int j = 0; j < 8; ++j)
    sv[j] = f2bf(w1n*v[j+1] + w0n*v[j+2] + w2n*v[j]);
  int nt = e >> 6, r = e & 63;
  int kt2 = d0 >> 6, c = d0 & 63;
  char* tile = (char*)Gt + (size_t)((h * NNT + nt) * NKT2 + kt2) * TILEB;
  *(short8*)(tile + swz(r, c * 2)) = sv;
}

// y[R,e] = sum_d x[R,d] * G[R%8][e,d]; R = h + 8*t
// B-strip (full K x 64 cols, 64 KiB) LDS-resident; ONE barrier per block.
// 8 waves free-run: A global->reg->bf16 (quarter-K staged), B ds_read, MFMA.
__global__ __launch_bounds__(512, 4) void gemm_kernel(const float* __restrict__ x,
                                                      const short* __restrict__ Gt,
                                                      float* __restrict__ out) {
  int bid = blockIdx.x;          // 1024 blocks
  int h   = bid & 7;             // head == XCD
  int idx = bid >> 3;
  int nt  = idx & 7;             // nt fastest: co-resident strips share x in L2
  int mt  = idx >> 3;            // 16 mtiles of 512 rows
  int tid  = threadIdx.x;
  int lane = tid & 63;
  int wid  = tid >> 6;           // 8 waves
  int ln = lane & 15, lh = lane >> 4;

  __shared__ char Blds[65536];   // [kt2][64r][64k] bf16, swizzled

  // --- stage whole B strip (64 KiB), linear copy of pre-swizzled images ---
  const char* Bsrc = (const char*)Gt + (size_t)(h * NNT + nt) * NKT2 * TILEB;
  #pragma unroll
  for (int p = 0; p < 8; ++p)
    __builtin_amdgcn_global_load_lds((const void*)(Bsrc + p * 8192 + tid * 16),
                                     (void*)(Blds + p * 8192 + wid * 1024), 16, 0, 0);

  // chunk-0 A loads issued before the barrier (overlap with B staging)
  float4 raw[8];
  bf16x8 afk[4];
  {
    const float* Arow = x + (size_t)(h + 8 * ((size_t)mt * 512 + wid * 64 + ln)) * DM + lh * 8;
    #pragma unroll
    for (int k4 = 0; k4 < 4; ++k4) {
      raw[2*k4]   = *(const float4*)(Arow + k4 * 32);
      raw[2*k4+1] = *(const float4*)(Arow + k4 * 32 + 4);
    }
  }
  __syncthreads();               // the ONLY barrier

  int sx = (ln & 7) << 4;        // per-lane xor (row&7 == ln&7 for rows n*16+ln)
  int rowb[4];
  #pragma unroll
  for (int n = 0; n < 4; ++n) rowb[n] = (n * 16 + ln) * 128;

  f32x4 acc[4];

  #pragma unroll 1
  for (int chunk = 0; chunk < 4; ++chunk) {
    int t0 = mt * 512 + wid * 64 + chunk * 16;
    const float* Arow = x + (size_t)(h + 8 * ((size_t)t0 + ln)) * DM + lh * 8;
    #pragma unroll
    for (int n = 0; n < 4; ++n) acc[n] = (f32x4){0.f, 0.f, 0.f, 0.f};

    if (chunk != 0) {            // chunk 0's q0 already in flight
      #pragma unroll
      for (int k4 = 0; k4 < 4; ++k4) {
        raw[2*k4]   = *(const float4*)(Arow + k4 * 32);
        raw[2*k4+1] = *(const float4*)(Arow + k4 * 32 + 4);
      }
    }

    #pragma unroll
    for (int q = 0; q < 4; ++q) {
      // convert current quarter (waits its loads)
      #pragma unroll
      for (int k4 = 0; k4 < 4; ++k4) {
        bf16x8 v;
        v[0]=(__bf16)raw[2*k4].x;   v[1]=(__bf16)raw[2*k4].y;
        v[2]=(__bf16)raw[2*k4].z;   v[3]=(__bf16)raw[2*k4].w;
        v[4]=(__bf16)raw[2*k4+1].x; v[5]=(__bf16)raw[2*k4+1].y;
        v[6]=(__bf16)raw[2*k4+1].z; v[7]=(__bf16)raw[2*k4+1].w;
        afk[k4] = v;
      }
      // issue next quarter's loads (raw dead after cvt)
      if (q < 3) {
        #pragma unroll
        for (int k4 = 0; k4 < 4; ++k4) {
          raw[2*k4]   = *(const float4*)(Arow + (q+1) * 128 + k4 * 32);
          raw[2*k4+1] = *(const float4*)(Arow + (q+1) * 128 + k4 * 32 + 4);
        }
      }
      // compute 4 k-steps: B ds_read + MFMA (loads fly underneath)
      #pragma unroll
      for (int k4 = 0; k4 < 4; ++k4) {
        int kt = q * 4 + k4;
        const char* tb = Blds + (kt >> 1) * 8192;
        int wq = (((kt & 1) << 6) | (lh << 4)) ^ sx;
        bf16x8 bfr[4];
        #pragma unroll
        for (int n = 0; n < 4; ++n)
          bfr[n] = *(const bf16x8*)(tb + rowb[n] + wq);
        #pragma unroll
        for (int n = 0; n < 4; ++n)
          acc[n] = __builtin_amdgcn_mfma_f32_16x16x32_bf16(afk[k4], bfr[n], acc[n], 0, 0, 0);
      }
    }

    // store chunk: C/D col = lane&15 (-> e), row = lh*4 + j (-> t)
    int ecol = nt * BN + ln;
    int Rb = h + 8 * (t0 + lh * 4);
    #pragma unroll
    for (int j = 0; j < 4; ++j) {
      float* orow = out + (size_t)(Rb + 8 * j) * DM + ecol;
      #pragma unroll
      for (int n = 0; n < 4; ++n)
        orow[n * 16] = acc[n][j];
    }
  }
}

extern "C" void kernel_launch(void* const* d_in, const int* in_sizes, int n_in,
                              void* d_out, int out_size, void* d_ws, size_t ws_size,
                              hipStream_t stream) {
  const float* x   = (const float*)d_in[0];
  const float* w   = (const float*)d_in[1];
  const float* fcw = (const float*)d_in[2];
  float* out = (float*)d_out;
  short* Gt  = (short*)d_ws;   // 8h * 8nt * 8kt2 * 8KiB = 4 MiB pre-swizzled

  hipLaunchKernelGGL(build_g_kernel, dim3((8 * DM * DM / 8) / 256), dim3(256), 0, stream,
                     w, fcw, Gt);
  hipLaunchKernelGGL(gemm_kernel, dim3(8 * NNT * 16), dim3(512), 0, stream,
                     x, Gt, out);
}

// Round 13
// 85.443 us; speedup vs baseline: 5.6328x; 5.6328x over previous
//
#include <hip/hip_runtime.h>

typedef __attribute__((ext_vector_type(8))) __bf16  bf16x8;
typedef __attribute__((ext_vector_type(8))) short   short8;
typedef __attribute__((ext_vector_type(4))) float   f32x4;

#define DM   512
#define BM   128
#define BN   128
#define BK   32
#define NNT  4                 // n-tiles (512/128)
#define NKT  16                // k-tiles (512/32)
#define TILEB (BN*BK*2)        // 8 KiB per tile image

__device__ __forceinline__ short f2bf(float f) {
  union { float f; unsigned u; } v; v.f = f;
  unsigned r = v.u + 0x7fffu + ((v.u >> 16) & 1u);   // RNE
  return (short)(r >> 16);
}

// Bijective slot layout for a [128 r][32 k] bf16 tile (8 KiB):
//   16-B slot for (row r, k-slot s) lives at (r>>3)*512 + ((r&7) + 8*s)*16.
// A frag read (16 rows x 4 slots across 64 lanes) hits 64 DISTINCT slots with
// uniform bank coverage -> zero counted LDS conflicts (structural 8-deep min).
__device__ __forceinline__ int slotA(int r, int s) {
  return (r >> 3) * 512 + (((r & 7) + (s << 3)) << 4);
}

// Fold softmax(taps) + conv into per-head G[h][e][d], stored as slot-permuted
// per-(h,nt,kt) 128x32 tile images. 8 d's (= one 16-B slot... 2 slots) /thread.
__global__ void build_g_kernel(const float* __restrict__ w,
                               const float* __restrict__ fcw,
                               short* __restrict__ Gt) {
  int idx = blockIdx.x * 256 + threadIdx.x;   // 8*512*512/8 threads
  int h  = idx >> 15;
  int t  = idx & 32767;
  int e  = t >> 6;
  int d0 = (t & 63) << 3;
  float w0 = w[h*3+0], w1 = w[h*3+1], w2 = w[h*3+2];
  float mx = fmaxf(w0, fmaxf(w1, w2));
  float e0 = __expf(w0-mx), e1 = __expf(w1-mx), e2 = __expf(w2-mx);
  float inv = 1.0f / (e0 + e1 + e2);
  float w0n = e0*inv, w1n = e1*inv, w2n = e2*inv;
  const float* row = fcw + e * DM;
  float v[10];
  v[0] = (d0 > 0) ? row[d0-1] : 0.0f;
  float4 a = *(const float4*)(row + d0);
  float4 b = *(const float4*)(row + d0 + 4);
  v[1]=a.x; v[2]=a.y; v[3]=a.z; v[4]=a.w;
  v[5]=b.x; v[6]=b.y; v[7]=b.z; v[8]=b.w;
  v[9] = (d0 + 8 < DM) ? row[d0+8] : 0.0f;
  short8 sv;
  #pragma unroll
  for (int j = 0; j < 8; ++j)
    sv[j] = f2bf(w1n*v[j+1] + w0n*v[j+2] + w2n*v[j]);
  int nt = e >> 7, r = e & 127;
  int kt = d0 >> 5;
  int s  = (d0 >> 3) & 3;        // 16-B k-slot within the 32-k tile
  char* tile = (char*)Gt + (size_t)((h * NNT + nt) * NKT + kt) * TILEB;
  *(short8*)(tile + slotA(r, s)) = sv;
}

// y[R,e] = sum_d x[R,d] * G[R%8][e,d]; R = h + 8*t
// R9 structure (4 blocks/CU, 32 KiB LDS, 1-barrier prefetch loop) with the
// bijective slot layout (0 LDS conflicts) and native bf16 casts.
__global__ __launch_bounds__(256, 4) void gemm_kernel(const float* __restrict__ x,
                                                      const short* __restrict__ Gt,
                                                      float* __restrict__ out) {
  int bid = blockIdx.x;          // 2048 blocks = 8/CU
  int h   = bid & 7;             // head == XCD
  int idx = bid >> 3;
  int nt  = idx & 3;             // nt fastest: co-scheduled nt-quads share A in L2
  int mt  = idx >> 2;            // 64 mtiles
  int tid  = threadIdx.x;
  int lane = tid & 63;
  int wid  = tid >> 6;
  int wr = wid >> 1, wc = wid & 1;   // 2x2 wave grid, 64x64 per wave
  int ln = lane & 15, sf = lane >> 4;

  __shared__ short Alds[2][BM * BK];   // 2 x 8 KiB slot-permuted
  __shared__ short Blds[2][BN * BK];   // 2 x 8 KiB slot-permuted

  const char* Bsrc0 = (const char*)Gt + (size_t)(h * NNT + nt) * NKT * TILEB;
  const float* Abase = x + (size_t)(h + 8 * (size_t)mt * BM) * DM;

  float4 ap[4];   // A prefetch regs (16 VGPR)

  auto loadA = [&](int kt) {
    #pragma unroll
    for (int p = 0; p < 2; ++p) {
      int r = (tid >> 2) + 64 * p;
      const float* xr = Abase + (size_t)r * 8 * DM + kt * BK + (tid & 3) * 8;
      ap[2*p]   = *(const float4*)xr;
      ap[2*p+1] = *(const float4*)(xr + 4);
    }
  };
  auto stageB = [&](int kt, int buf) {   // 2 x gload_lds dwordx4, linear copy
    const char* src = Bsrc0 + kt * TILEB;
    char* dst = (char*)Blds[buf];
    #pragma unroll
    for (int p = 0; p < 2; ++p)
      __builtin_amdgcn_global_load_lds((const void*)(src + p * 4096 + tid * 16),
                                       (void*)(dst + p * 4096 + wid * 1024), 16, 0, 0);
  };
  auto writeA = [&](int buf) {   // native casts -> v_cvt_pk_bf16_f32
    char* dst = (char*)Alds[buf];
    #pragma unroll
    for (int p = 0; p < 2; ++p) {
      int r = (tid >> 2) + 64 * p;
      bf16x8 v;
      v[0]=(__bf16)ap[2*p].x;   v[1]=(__bf16)ap[2*p].y;
      v[2]=(__bf16)ap[2*p].z;   v[3]=(__bf16)ap[2*p].w;
      v[4]=(__bf16)ap[2*p+1].x; v[5]=(__bf16)ap[2*p+1].y;
      v[6]=(__bf16)ap[2*p+1].z; v[7]=(__bf16)ap[2*p+1].w;
      *(bf16x8*)(dst + slotA(r, tid & 3)) = v;
    }
  };

  f32x4 acc[4][4] = {};   // wave tile 64x64

  auto computeTile = [&](int cur) {
    const char* Ap = (const char*)Alds[cur];
    const char* Bp = (const char*)Blds[cur];
    bf16x8 af[4], bfr[4];
    #pragma unroll
    for (int m = 0; m < 4; ++m)
      af[m] = *(const bf16x8*)(Ap + slotA(wr*64 + m*16 + ln, sf));
    #pragma unroll
    for (int n = 0; n < 4; ++n)
      bfr[n] = *(const bf16x8*)(Bp + slotA(wc*64 + n*16 + ln, sf));
    #pragma unroll
    for (int m = 0; m < 4; ++m)
      #pragma unroll
      for (int n = 0; n < 4; ++n)
        acc[m][n] = __builtin_amdgcn_mfma_f32_16x16x32_bf16(af[m], bfr[n], acc[m][n], 0, 0, 0);
  };

  // prologue: tile 0 -> buf 0
  loadA(0);
  stageB(0, 0);
  writeA(0);
  __syncthreads();

  for (int kt = 0; kt < NKT; ++kt) {
    int cur = kt & 1, nxt = cur ^ 1;
    if (kt + 1 < NKT) {            // issue next tile's loads before compute
      loadA(kt + 1);
      stageB(kt + 1, nxt);
    }
    computeTile(cur);
    if (kt + 1 < NKT) writeA(nxt); // convert + ds_write after compute
    __syncthreads();               // boundary drain
  }

  // epilogue: C/D layout col = lane&15, row = (lane>>4)*4 + j
  int e0 = nt * BN + wc * 64 + ln;
  #pragma unroll
  for (int m = 0; m < 4; ++m) {
    int tq = mt * BM + wr * 64 + m * 16 + (sf << 2);
    #pragma unroll
    for (int j = 0; j < 4; ++j) {
      int R = h + 8 * (tq + j);
      float* orow = out + (size_t)R * DM + e0;
      #pragma unroll
      for (int n = 0; n < 4; ++n)
        orow[n * 16] = acc[m][n][j];
    }
  }
}

extern "C" void kernel_launch(void* const* d_in, const int* in_sizes, int n_in,
                              void* d_out, int out_size, void* d_ws, size_t ws_size,
                              hipStream_t stream) {
  const float* x   = (const float*)d_in[0];
  const float* w   = (const float*)d_in[1];
  const float* fcw = (const float*)d_in[2];
  float* out = (float*)d_out;
  short* Gt  = (short*)d_ws;   // 8*4*16 tiles * 8 KiB = 4 MiB slot-permuted

  hipLaunchKernelGGL(build_g_kernel, dim3((8 * DM * DM / 8) / 256), dim3(256), 0, stream,
                     w, fcw, Gt);
  hipLaunchKernelGGL(gemm_kernel, dim3(8 * 64 * NNT), dim3(256), 0, stream,
                     x, Gt, out);
}